// Round 23
// baseline (64.566 us; speedup 1.0000x reference)
//
#include <hip/hip_runtime.h>

// Problem constants: B=8, S=2048, D=512, G=2, V=320, CV=128
#define M_ROWS 16384   // B*S
#define K_DIM  512
#define N_COLS 640     // G*V
#define V_CODES 320
#define CV_DIM 128

typedef _Float16 half8 __attribute__((ext_vector_type(8)));
typedef _Float16 half4v __attribute__((ext_vector_type(4)));
typedef float floatx4 __attribute__((ext_vector_type(4)));

#define SBAR()  __builtin_amdgcn_sched_barrier(0)
#define WAITV(N) asm volatile("s_waitcnt vmcnt(" #N ")" ::: "memory")
// Forced register-destination B load: asm output is opaque -> allocator must
// keep the ring live (r9's compiler-collapsed prefetch, now enforced).
#define LOADB(dst, p) asm volatile("global_load_dwordx4 %0, %1, off" \
                                   : "=v"(dst) : "v"(p))

// ---------------------------------------------------------------------------
// Kernel 0: prepW — LDS-tiled transpose W (512,640) f32 -> Wt (640,512) f16;
// block 320 zeroes the global marginal.
// ---------------------------------------------------------------------------
__global__ __launch_bounds__(256)
void prepW(const float* __restrict__ W, _Float16* __restrict__ Wt,
           float* __restrict__ marginal) {
    __shared__ float tile[32][33];
    const int b = blockIdx.x, t = threadIdx.x;
    if (b == 320) {
        for (int i = t; i < 640; i += 256) marginal[i] = 0.f;
        return;
    }
    const int n0 = (b % 20) * 32, k0 = (b / 20) * 32;
    {
        const int kk = t >> 3, nn4 = (t & 7) << 2;
        const float4 w = *(const float4*)(W + (size_t)(k0 + kk) * 640 + n0 + nn4);
        tile[kk][nn4 + 0] = w.x; tile[kk][nn4 + 1] = w.y;
        tile[kk][nn4 + 2] = w.z; tile[kk][nn4 + 3] = w.w;
    }
    __syncthreads();
    {
        const int nn = t >> 3, kk4 = (t & 7) << 2;
        half4v h = {(_Float16)tile[kk4 + 0][nn], (_Float16)tile[kk4 + 1][nn],
                    (_Float16)tile[kk4 + 2][nn], (_Float16)tile[kk4 + 3][nn]};
        *(half4v*)(Wt + (size_t)(n0 + nn) * 512 + k0 + kk4) = h;
    }
}

// ---------------------------------------------------------------------------
// Fused kernel (r9 geometry + ASM-FORCED 2-deep B register ring):
// grid (256 bm, 2 g), 256 threads = 4 waves.
// A-tile (64x512) staged ONCE to LDS (f32->f16, XOR-swizzle chunk^(row&7)).
// Wave w owns ALL 64 token-rows x cols [w*80, w*80+80): acc[4 mt][5 nt].
// B: per-wave-unique fragments loaded straight from L2-resident Wt into an
// explicit asm register ring (rb0/rb1), issued 2 K-steps ahead; per step:
// s_waitcnt vmcnt(5) + sched_barrier -> 4 ds_read af -> 20 MFMA -> reissue.
// NO barriers and NO B LDS traffic in the K-loop.
// Epilogue: r9-verified cross-wave combine + marginal + cv gather/out.
// ---------------------------------------------------------------------------
__global__ __launch_bounds__(256, 2)
void fused(const float* __restrict__ A, const _Float16* __restrict__ Bt,
           const float* __restrict__ bias, const float* __restrict__ gum,
           const float* __restrict__ cv, float* __restrict__ out,
           float* __restrict__ marginal) {
    __shared__ _Float16 As[64 * 512];   // 64 KB, swizzled
    __shared__ float wbest[4][64];
    __shared__ int   wbidx[4][64];
    __shared__ float wsum[4][64];
    __shared__ int   fbidx[64];
    __shared__ float finv[64];

    const int t = threadIdx.x;
    const int wave = t >> 6, lane = t & 63;
    const int bm = blockIdx.x, g = blockIdx.y;
    const int c = lane & 15, kq = lane >> 4;

    // ---- prologue: stage A tile once (f32 -> f16, swizzled) ----
    {
        const int am = t >> 2;              // row 0..63
        const int kb = (t & 3) * 128;       // k base (4 threads/row)
        const float* Ap = A + (size_t)(bm * 64 + am) * 512 + kb;
#pragma unroll
        for (int i = 0; i < 16; ++i) {
            const float4 v0 = *(const float4*)(Ap + i * 8);
            const float4 v1 = *(const float4*)(Ap + i * 8 + 4);
            const half8 h = {(_Float16)v0.x, (_Float16)v0.y, (_Float16)v0.z,
                             (_Float16)v0.w, (_Float16)v1.x, (_Float16)v1.y,
                             (_Float16)v1.z, (_Float16)v1.w};
            const int chunk = ((kb >> 3) + i) ^ (am & 7);
            *(half8*)((char*)As + am * 1024 + chunk * 16) = h;
        }
    }
    __syncthreads();   // drains vmcnt/lgkmcnt -> ring counting starts at 0

    floatx4 acc[4][5];
#pragma unroll
    for (int mt = 0; mt < 4; ++mt)
#pragma unroll
        for (int nt = 0; nt < 5; ++nt) acc[mt][nt] = (floatx4){0.f, 0.f, 0.f, 0.f};

    const _Float16* Bw = Bt + (size_t)g * V_CODES * K_DIM
                            + (size_t)(wave * 80 + c) * K_DIM + kq * 8;

    half8 rb0[5], rb1[5];
    // issue tiles 0 and 1 into the ring
#pragma unroll
    for (int nt = 0; nt < 5; ++nt) LOADB(rb0[nt], (Bw + (size_t)nt * 16 * K_DIM));
#pragma unroll
    for (int nt = 0; nt < 5; ++nt) LOADB(rb1[nt], (Bw + (size_t)nt * 16 * K_DIM + 32));

    auto STEP = [&](int kt, half8 (&rb)[5]) {
        half8 af[4];
#pragma unroll
        for (int mt = 0; mt < 4; ++mt) {
            const int ra = mt * 16 + c;
            const int chunk = (kt * 4 + kq) ^ (ra & 7);
            af[mt] = *(const half8*)((const char*)As + ra * 1024 + chunk * 16);
        }
        __builtin_amdgcn_s_setprio(1);
#pragma unroll
        for (int mt = 0; mt < 4; ++mt)
#pragma unroll
            for (int nt = 0; nt < 5; ++nt)
                acc[mt][nt] = __builtin_amdgcn_mfma_f32_16x16x32_f16(
                    af[mt], rb[nt], acc[mt][nt], 0, 0, 0);
        __builtin_amdgcn_s_setprio(0);
    };
    auto ISSUE = [&](half8 (&rb)[5], int ktN) {
#pragma unroll
        for (int nt = 0; nt < 5; ++nt)
            LOADB(rb[nt], (Bw + (size_t)nt * 16 * K_DIM + ktN * 32));
    };

    // ---- barrier-free K loop: steps 0..13 (ring reissued 2 ahead) ----
#pragma unroll
    for (int kt = 0; kt < 14; kt += 2) {
        WAITV(5); SBAR();              // tile kt landed; kt+1 still in flight
        STEP(kt, rb0);
        ISSUE(rb0, kt + 2);
        WAITV(5); SBAR();              // tile kt+1 landed; kt+2 in flight
        STEP(kt + 1, rb1);
        ISSUE(rb1, kt + 3);
    }
    // ---- steps 14, 15 (no reissue) ----
    WAITV(5); SBAR();
    STEP(14, rb0);
    WAITV(0); SBAR();
    STEP(15, rb1);

    // ---- epilogue (r9-verified) ----
    float bcol[5];
#pragma unroll
    for (int nt = 0; nt < 5; ++nt)
        bcol[nt] = bias[g * V_CODES + wave * 80 + nt * 32 / 2 + c];  // nt*16+c
#pragma unroll
    for (int mt = 0; mt < 4; ++mt)
#pragma unroll
        for (int nt = 0; nt < 5; ++nt)
#pragma unroll
            for (int rg = 0; rg < 4; ++rg) acc[mt][nt][rg] += bcol[nt];

    __syncthreads();   // A-LDS no longer needed; scratch phase begins

    // per-(mt,rg): quarter-wave argmax(L+gumbel) + exp-in-place + sum partials
#pragma unroll
    for (int mt = 0; mt < 4; ++mt) {
#pragma unroll
        for (int rg = 0; rg < 4; ++rg) {
            const int r = mt * 16 + kq * 4 + rg;    // block-local token row
            const float* gr = gum + ((size_t)(bm * 64 + r) * 2 + g) * V_CODES
                              + wave * 80 + c;
            float best = -1e30f; int bidx = 0;
#pragma unroll
            for (int nt = 0; nt < 5; ++nt) {
                const float nz = acc[mt][nt][rg] + gr[nt * 16];
                const int v = wave * 80 + nt * 16 + c;
                if (nz > best) { best = nz; bidx = v; }
            }
#pragma unroll
            for (int mask = 1; mask <= 8; mask <<= 1) {
                const float ob = __shfl_xor(best, mask);
                const int   oi = __shfl_xor(bidx, mask);
                if (ob > best || (ob == best && oi < bidx)) { best = ob; bidx = oi; }
            }
            float s = 0.f;
#pragma unroll
            for (int nt = 0; nt < 5; ++nt) {
                const float e = __expf(acc[mt][nt][rg]);
                acc[mt][nt][rg] = e;                 // keep exp for marginal
                s += e;
            }
#pragma unroll
            for (int mask = 1; mask <= 8; mask <<= 1) s += __shfl_xor(s, mask);
            if (c == 0) {
                wbest[wave][r] = best;
                wbidx[wave][r] = bidx;
                wsum[wave][r]  = s;
            }
        }
    }
    __syncthreads();

    // cross-wave combine: final argmax + 1/sum per row
    if (t < 64) {
        float best = wbest[0][t]; int bi = wbidx[0][t];
        float s = wsum[0][t];
#pragma unroll
        for (int w = 1; w < 4; ++w) {
            const float ob = wbest[w][t]; const int oi = wbidx[w][t];
            if (ob > best || (ob == best && oi < bi)) { best = ob; bi = oi; }
            s += wsum[w][t];
        }
        fbidx[t] = bi;
        finv[t] = 1.f / s;
    }
    __syncthreads();

    // marginal: mcon[nt] = sum over this wave's rows of exp * inv
    float mcon[5];
#pragma unroll
    for (int nt = 0; nt < 5; ++nt) mcon[nt] = 0.f;
#pragma unroll
    for (int mt = 0; mt < 4; ++mt) {
#pragma unroll
        for (int rg = 0; rg < 4; ++rg) {
            const float iv = finv[mt * 16 + kq * 4 + rg];
#pragma unroll
            for (int nt = 0; nt < 5; ++nt) mcon[nt] += acc[mt][nt][rg] * iv;
        }
    }
#pragma unroll
    for (int nt = 0; nt < 5; ++nt) {
        mcon[nt] += __shfl_xor(mcon[nt], 16);
        mcon[nt] += __shfl_xor(mcon[nt], 32);
    }
    if (lane < 16) {
#pragma unroll
        for (int nt = 0; nt < 5; ++nt)
            atomicAdd(marginal + g * V_CODES + wave * 80 + nt * 16 + c, mcon[nt]);
    }

    // out: wave writes rows [wave*16, wave*16+16), one-hot codevector gather
#pragma unroll
    for (int rr = 0; rr < 4; ++rr) {
        const int row = wave * 16 + kq * 4 + rr;
        const int bi = fbidx[row];
        const float4* cvp = (const float4*)(cv + ((size_t)g * V_CODES + bi) * CV_DIM)
                            + c * 2;
        const float4 v0 = cvp[0], v1 = cvp[1];
        float4* op = (float4*)(out + (size_t)(bm * 64 + row) * 256 + g * CV_DIM)
                     + c * 2;
        op[0] = v0; op[1] = v1;
    }
}

// ---------------------------------------------------------------------------
// Kernel 2: finalize perplexity from the global marginal (640 floats).
// ---------------------------------------------------------------------------
__global__ __launch_bounds__(640)
void finalize(const float* __restrict__ marginal, float* __restrict__ perp_out) {
    __shared__ float terms[640];
    __shared__ float gsum[2];
    const int t = threadIdx.x;

    const float m = marginal[t] * (1.0f / (float)M_ROWS);
    terms[t] = -m * __logf(m + 1e-7f);
    __syncthreads();

    if (t < 128) {
        const int g = t >> 6, lane = t & 63;
        float e = 0.f;
#pragma unroll
        for (int j = 0; j < 5; ++j) e += terms[g * V_CODES + lane + 64 * j];
#pragma unroll
        for (int off = 32; off; off >>= 1) e += __shfl_down(e, off);
        if (lane == 0) gsum[g] = e;
    }
    __syncthreads();
    if (t == 0) perp_out[0] = __expf(gsum[0]) + __expf(gsum[1]);
}

// ---------------------------------------------------------------------------
extern "C" void kernel_launch(void* const* d_in, const int* in_sizes, int n_in,
                              void* d_out, int out_size, void* d_ws, size_t ws_size,
                              hipStream_t stream) {
    (void)in_sizes; (void)n_in; (void)out_size; (void)ws_size;
    const float* hs = (const float*)d_in[0];   // (8,2048,512) f32
    const float* W  = (const float*)d_in[1];   // (512,640)    f32
    const float* bi = (const float*)d_in[2];   // (640,)       f32
    const float* cv = (const float*)d_in[3];   // (1,640,128)  f32
    const float* gu = (const float*)d_in[4];   // (32768,320)  f32
    float* out = (float*)d_out;                // 16384*256 + 1

    // ws: Wt f16 (640 KB) + marginal (640 f32)
    _Float16* Wt       = (_Float16*)d_ws;
    float*    marginal = (float*)(Wt + (size_t)N_COLS * K_DIM);

    prepW<<<321, 256, 0, stream>>>(W, Wt, marginal);
    fused<<<dim3(256, 2), 256, 0, stream>>>(hs, Wt, bi, gu, cv, out, marginal);
    finalize<<<1, 640, 0, stream>>>(marginal, out + (size_t)M_ROWS * 256);
}

// Round 24
// 48.346 us; speedup vs baseline: 1.3355x; 1.3355x over previous
//
#include <hip/hip_runtime.h>

// Problem constants: B=8, S=2048, D=512, G=2, V=320, CV=128
#define M_ROWS 16384   // B*S
#define K_DIM  512
#define N_COLS 640     // G*V
#define V_CODES 320
#define CV_DIM 128

typedef _Float16 half8 __attribute__((ext_vector_type(8)));
typedef _Float16 half4v __attribute__((ext_vector_type(4)));
typedef float floatx4 __attribute__((ext_vector_type(4)));

__device__ inline void gll16(const void* g, void* l) {
    __builtin_amdgcn_global_load_lds(
        (const __attribute__((address_space(1))) void*)g,
        (__attribute__((address_space(3))) void*)l, 16, 0, 0);
}

#define SBAR()  __builtin_amdgcn_sched_barrier(0)
#define WAITV(N) asm volatile("s_waitcnt vmcnt(" #N ")" ::: "memory")
#define WAITL() asm volatile("s_waitcnt lgkmcnt(0)" ::: "memory")

// ---------------------------------------------------------------------------
// Kernel 0: prepW — LDS-tiled transpose W (512,640) f32 -> Wt (640,512) f16;
// block 320 zeroes the global marginal.
// ---------------------------------------------------------------------------
__global__ __launch_bounds__(256)
void prepW(const float* __restrict__ W, _Float16* __restrict__ Wt,
           float* __restrict__ marginal) {
    __shared__ float tile[32][33];
    const int b = blockIdx.x, t = threadIdx.x;
    if (b == 320) {
        for (int i = t; i < 640; i += 256) marginal[i] = 0.f;
        return;
    }
    const int n0 = (b % 20) * 32, k0 = (b / 20) * 32;
    {
        const int kk = t >> 3, nn4 = (t & 7) << 2;
        const float4 w = *(const float4*)(W + (size_t)(k0 + kk) * 640 + n0 + nn4);
        tile[kk][nn4 + 0] = w.x; tile[kk][nn4 + 1] = w.y;
        tile[kk][nn4 + 2] = w.z; tile[kk][nn4 + 3] = w.w;
    }
    __syncthreads();
    {
        const int nn = t >> 3, kk4 = (t & 7) << 2;
        half4v h = {(_Float16)tile[kk4 + 0][nn], (_Float16)tile[kk4 + 1][nn],
                    (_Float16)tile[kk4 + 2][nn], (_Float16)tile[kk4 + 3][nn]};
        *(half4v*)(Wt + (size_t)(n0 + nn) * 512 + k0 + kk4) = h;
    }
}

// ---------------------------------------------------------------------------
// Fused kernel (round-15/22, measured optimum): grid (256 bm, 2 g), 256
// threads = 4 waves; wave mi owns 16 rows x 320 cols (acc[20], 16x16x32).
// K-loop: counted-vmcnt 2-deep pipeline — per iter: compute(cur) -> raw
// s_barrier -> issue tile kt+2 (2 A-reg loads + 5 B gll16, stay IN FLIGHT)
// -> ds_write A(kt+1) -> s_waitcnt vmcnt(7) -> lgkmcnt(0) -> raw s_barrier.
// Epilogue: in-register argmax(L+gumbel) (16-lane butterflies) + noise-free
// softmax + cv gather/out + marginal via LDS + global atomics.
// ---------------------------------------------------------------------------
__global__ __launch_bounds__(256, 2)
void fused(const float* __restrict__ A, const _Float16* __restrict__ Bt,
           const float* __restrict__ bias, const float* __restrict__ gum,
           const float* __restrict__ cv, float* __restrict__ out,
           float* __restrict__ marginal) {
    __shared__ _Float16 Bs[2][320 * 32];   // 2 x 20 KB
    __shared__ _Float16 As[2][64 * 32];    // 2 x 4 KB
    __shared__ float smarg[320];
    const int t = threadIdx.x;
    const int wave = t >> 6, lane = t & 63;
    const int bm = blockIdx.x, g = blockIdx.y;
    const int mi = wave;
    const int c = lane & 15, kq = lane >> 4;

    for (int i = t; i < 320; i += 256) smarg[i] = 0.f;

    floatx4 acc[20];
#pragma unroll
    for (int nt = 0; nt < 20; ++nt) acc[nt] = (floatx4){0.f, 0.f, 0.f, 0.f};

    // A staging map (round-8): row am, 16B chunk ad, swizzle ^(am&3)
    const int am = t >> 2, ad = t & 3;
    const int a_wr = am * 64 + ((ad ^ (am & 3)) << 4);
    const float* Aptr = A + (size_t)(bm * 64 + am) * 512 + ad * 8;

    const _Float16* Bg = Bt + (size_t)g * V_CODES * K_DIM;

    float4 avA0, avA1;   // pending A data (next tile to be ds_written)
    float4 avN0, avN1;

    auto ISSUE_B = [&](int buf, int k0) {
#pragma unroll
        for (int s = 0; s < 5; ++s) {
            const int q = t + 256 * s;               // 0..1279
            const int n = q >> 2, j = q & 3;         // B-row, chunk
            gll16(Bg + (size_t)n * 512 + k0 + ((j ^ (n & 3)) << 3),
                  (char*)(&Bs[buf][0]) + q * 16);
        }
    };
    auto WRITE_A = [&](int buf, const float4& v0, const float4& v1) {
        const half8 h = {(_Float16)v0.x, (_Float16)v0.y, (_Float16)v0.z,
                         (_Float16)v0.w, (_Float16)v1.x, (_Float16)v1.y,
                         (_Float16)v1.z, (_Float16)v1.w};
        *(half8*)((char*)(&As[buf][0]) + a_wr) = h;
    };
    auto COMPUTE = [&](int cur) {
        const int ra = mi * 16 + c;
        const half8 af = *(const half8*)((const char*)(&As[cur][0]) +
                          ra * 64 + ((kq ^ (ra & 3)) << 4));
        __builtin_amdgcn_s_setprio(1);
#pragma unroll
        for (int nt = 0; nt < 20; ++nt) {
            const int rb = nt * 16 + c;
            const half8 bf = *(const half8*)((const char*)(&Bs[cur][0]) +
                              rb * 64 + ((kq ^ (rb & 3)) << 4));
            acc[nt] = __builtin_amdgcn_mfma_f32_16x16x32_f16(af, bf, acc[nt], 0, 0, 0);
        }
        __builtin_amdgcn_s_setprio(0);
    };

    // ---- prologue: tiles 0 and 1 ----
    avA0 = *(const float4*)(Aptr + 0);
    avA1 = *(const float4*)(Aptr + 4);
    ISSUE_B(0, 0);
    WRITE_A(0, avA0, avA1);          // compiler waits only the two A loads
    avA0 = *(const float4*)(Aptr + 32);
    avA1 = *(const float4*)(Aptr + 36);
    ISSUE_B(1, 32);
    SBAR(); WAITV(7);                // tile0's 5 B done (leaves 2A+5B of tile1)
    SBAR(); WAITL();
    SBAR(); __builtin_amdgcn_s_barrier(); SBAR();

    // ---- steady state: kt = 0..13 ----
    for (int kt = 0; kt < 14; ++kt) {
        const int cur = kt & 1;
        COMPUTE(cur);
        SBAR(); __builtin_amdgcn_s_barrier(); SBAR();   // readers of cur done
        avN0 = *(const float4*)(Aptr + (kt + 2) * 32);
        avN1 = *(const float4*)(Aptr + (kt + 2) * 32 + 4);
        ISSUE_B(cur, (kt + 2) * 32);                    // tile kt+2 -> cur
        WRITE_A(cur ^ 1, avA0, avA1);                   // A of tile kt+1
        SBAR(); WAITV(7);                               // tile kt+1's B done
        SBAR(); WAITL();
        SBAR(); __builtin_amdgcn_s_barrier(); SBAR();
        avA0 = avN0; avA1 = avN1;
    }
    // ---- kt = 14 ----
    COMPUTE(0);
    SBAR(); __builtin_amdgcn_s_barrier(); SBAR();
    WRITE_A(1, avA0, avA1);                             // A of tile 15
    SBAR(); WAITV(0);                                   // drain tile 15's B
    SBAR(); WAITL();
    SBAR(); __builtin_amdgcn_s_barrier(); SBAR();
    // ---- kt = 15 ----
    COMPUTE(1);

    // ---- epilogue ----
    float bcol[20];
#pragma unroll
    for (int nt = 0; nt < 20; ++nt) bcol[nt] = bias[g * V_CODES + nt * 16 + c];

    float mcontrib[20];
#pragma unroll
    for (int nt = 0; nt < 20; ++nt) mcontrib[nt] = 0.f;

#pragma unroll
    for (int rg = 0; rg < 4; ++rg) {
        const int ntok = bm * 64 + mi * 16 + kq * 4 + rg;   // token (per-lane)
        float lg[20];
#pragma unroll
        for (int nt = 0; nt < 20; ++nt) lg[nt] = acc[nt][rg] + bcol[nt];
        const float* gr = gum + ((size_t)ntok * 2 + g) * V_CODES + c;
        float gv[20];
#pragma unroll
        for (int nt = 0; nt < 20; ++nt) gv[nt] = gr[nt * 16];
        // per-lane argmax over this lane's 20 cols (lowest-index tie)
        float best = -1e30f; int bidx = 0;
#pragma unroll
        for (int nt = 0; nt < 20; ++nt) {
            const float nz = lg[nt] + gv[nt];
            const int v = nt * 16 + c;
            if (nz > best) { best = nz; bidx = v; }
        }
        // 16-lane all-reduce argmax (xor 1..8 stays within quarter-wave)
#pragma unroll
        for (int mask = 1; mask <= 8; mask <<= 1) {
            const float ob = __shfl_xor(best, mask);
            const int   oi = __shfl_xor(bidx, mask);
            if (ob > best || (ob == best && oi < bidx)) { best = ob; bidx = oi; }
        }
        // noise-free softmax (no max-sub: logits O(+-6), f32-exact enough)
        float s = 0.f;
#pragma unroll
        for (int nt = 0; nt < 20; ++nt) { lg[nt] = __expf(lg[nt]); s += lg[nt]; }
#pragma unroll
        for (int mask = 1; mask <= 8; mask <<= 1) s += __shfl_xor(s, mask);
        const float inv = 1.f / s;
#pragma unroll
        for (int nt = 0; nt < 20; ++nt) mcontrib[nt] += lg[nt] * inv;
        // codevector gather + straight-through output (one-hot row bidx)
        const float4* cvp = (const float4*)(cv + ((size_t)g * V_CODES + bidx) * CV_DIM)
                            + c * 2;
        const float4 v0 = cvp[0], v1 = cvp[1];
        float4* op = (float4*)(out + (size_t)ntok * 256 + g * CV_DIM) + c * 2;
        op[0] = v0; op[1] = v1;
    }

    // marginal: reduce 4 quarter-wave groups (same cols), LDS + global atomics
#pragma unroll
    for (int nt = 0; nt < 20; ++nt) {
        mcontrib[nt] += __shfl_xor(mcontrib[nt], 16);
        mcontrib[nt] += __shfl_xor(mcontrib[nt], 32);
    }
    if (lane < 16) {
#pragma unroll
        for (int nt = 0; nt < 20; ++nt)
            atomicAdd(&smarg[nt * 16 + c], mcontrib[nt]);
    }
    __syncthreads();
    for (int i = t; i < 320; i += 256)
        atomicAdd(marginal + g * V_CODES + i, smarg[i]);
}

// ---------------------------------------------------------------------------
// Kernel 2: finalize perplexity from the global marginal (640 floats).
// ---------------------------------------------------------------------------
__global__ __launch_bounds__(640)
void finalize(const float* __restrict__ marginal, float* __restrict__ perp_out) {
    __shared__ float terms[640];
    __shared__ float gsum[2];
    const int t = threadIdx.x;

    const float m = marginal[t] * (1.0f / (float)M_ROWS);
    terms[t] = -m * __logf(m + 1e-7f);
    __syncthreads();

    if (t < 128) {
        const int g = t >> 6, lane = t & 63;
        float e = 0.f;
#pragma unroll
        for (int j = 0; j < 5; ++j) e += terms[g * V_CODES + lane + 64 * j];
#pragma unroll
        for (int off = 32; off; off >>= 1) e += __shfl_down(e, off);
        if (lane == 0) gsum[g] = e;
    }
    __syncthreads();
    if (t == 0) perp_out[0] = __expf(gsum[0]) + __expf(gsum[1]);
}

// ---------------------------------------------------------------------------
extern "C" void kernel_launch(void* const* d_in, const int* in_sizes, int n_in,
                              void* d_out, int out_size, void* d_ws, size_t ws_size,
                              hipStream_t stream) {
    (void)in_sizes; (void)n_in; (void)out_size; (void)ws_size;
    const float* hs = (const float*)d_in[0];   // (8,2048,512) f32
    const float* W  = (const float*)d_in[1];   // (512,640)    f32
    const float* bi = (const float*)d_in[2];   // (640,)       f32
    const float* cv = (const float*)d_in[3];   // (1,640,128)  f32
    const float* gu = (const float*)d_in[4];   // (32768,320)  f32
    float* out = (float*)d_out;                // 16384*256 + 1

    // ws: Wt f16 (640 KB) + marginal (640 f32)
    _Float16* Wt       = (_Float16*)d_ws;
    float*    marginal = (float*)(Wt + (size_t)N_COLS * K_DIM);

    prepW<<<321, 256, 0, stream>>>(W, Wt, marginal);
    fused<<<dim3(256, 2), 256, 0, stream>>>(hs, Wt, bi, gu, cv, out, marginal);
    finalize<<<1, 640, 0, stream>>>(marginal, out + (size_t)M_ROWS * 256);
}